// Round 3
// baseline (1056.679 us; speedup 1.0000x reference)
//
#include <hip/hip_runtime.h>
#include <cstdint>
#include <cstddef>

#define N_NODES 100000
#define N_EDGES 1600000
// D_NODE=256, D_MSG=128, D_RBF=32, H=8, D_HEAD=16

#define M_PAD 100096   // 782*128
#define SCAN_NB 98     // ceil(N_NODES/1024)
#define CH 16          // CSR slots per chunk in k_node (matches MFMA M=16)

// ---- workspace layout (float offsets) ----
// XLR:    N*256 f32                      [xl | xr]
// ACCB:   M_PAD*128 bf16 (edge output)   = 6,406,144 floats
// CSRSE:  E int2 (src, edge-id)          = 3,200,000 floats
// ROW:    N+1 int (CSR row offsets)
// CNT:    N int (scatter cursors)        -- zeroed by k_pre
// DEGI:   N int (histogram)              -- zeroed by k_pre
// FLAGS:  128 int (scan flags + ticket)  -- zeroed by k_pre
// BCAT/WCOMBB/WCATB/WM2NB: folded weights
#define OFF_XLR    ((size_t)0)
#define OFF_ACCB   (OFF_XLR    + (size_t)N_NODES*256)      // 25,600,000
#define OFF_CSRSE  (OFF_ACCB   + (size_t)6406144)          // 32,006,144
#define OFF_ROW    (OFF_CSRSE  + (size_t)3200000)          // 35,206,144
#define OFF_CNT    (OFF_ROW    + (size_t)100016)
#define OFF_DEGI   (OFF_CNT    + (size_t)N_NODES)
#define OFF_FLAGS  (OFF_DEGI   + (size_t)N_NODES)          // 128 ints (ticket at [100])
#define OFF_BCAT   (OFF_FLAGS  + 128)
#define OFF_WCOMBB (OFF_BCAT   + 256)                      // 2048 floats = 4096 bf16
#define OFF_WCATB  (OFF_WCOMBB + 2048)                     // 32768 floats
#define OFF_WM2NB  (OFF_WCATB  + 32768)                    // 16384 floats
// total ~= 35.6M floats = 142 MB

typedef __attribute__((ext_vector_type(8))) short short8;
typedef __attribute__((ext_vector_type(4))) float float4v;

__device__ __forceinline__ unsigned short f2bf(float f) {
  unsigned u = __float_as_uint(f);
  unsigned r = (u + 0x7fff + ((u >> 16) & 1)) >> 16;
  return (unsigned short)r;
}

__device__ __forceinline__ uint4 pack8(float4 a, float4 b) {
  uint4 r;
  r.x = (unsigned)f2bf(a.x) | ((unsigned)f2bf(a.y) << 16);
  r.y = (unsigned)f2bf(a.z) | ((unsigned)f2bf(a.w) << 16);
  r.z = (unsigned)f2bf(b.x) | ((unsigned)f2bf(b.y) << 16);
  r.w = (unsigned)f2bf(b.z) | ((unsigned)f2bf(b.w) << 16);
  return r;
}

// ---------------- fused: fold weights + zero (cnt|degi|flags) ----------------
// blocks 0..400: weights work (idx-chained, as before)
// blocks 401..596: zero 200,128 ints starting at zbase (= ws+OFF_CNT)
__global__ __launch_bounds__(256) void k_pre(
    const float* __restrict__ Wl, const float* __restrict__ Wr,
    const float* __restrict__ We, const float* __restrict__ W_n2m,
    const float* __restrict__ W_r2m, const float* __restrict__ bl,
    const float* __restrict__ br, const float* __restrict__ W_m2n,
    unsigned short* __restrict__ WcatB, float* __restrict__ bcat,
    unsigned short* __restrict__ WcombB, unsigned short* __restrict__ Wm2nB,
    float* __restrict__ zbase) {
  const int b = blockIdx.x;
  const int tid = threadIdx.x;
  if (b >= 401) {
    unsigned i = (unsigned)(b - 401) * 256u + tid;
    if (i < 50032u) ((float4*)zbase)[i] = make_float4(0.f, 0.f, 0.f, 0.f);
    return;
  }
  int idx = b * 256 + tid;
  if (idx < 65536) {
    int o = idx >> 8, i = idx & 255;
    const float* wrow = (o < 128) ? (Wl + o * 128) : (Wr + (o - 128) * 128);
    float s = 0.f;
    for (int k = 0; k < 128; ++k) s += wrow[k] * W_n2m[k * 256 + i];
    WcatB[idx] = f2bf(s);
  } else if (idx < 65536 + 256) {
    int o = idx - 65536;
    bcat[o] = (o < 128) ? bl[o] : br[o - 128];
  } else if (idx < 65536 + 256 + 4096) {
    int q = idx - (65536 + 256);
    int j = q >> 7, o = q & 127;
    float s = 0.f;
    for (int k = 0; k < 128; ++k) s += We[o * 128 + k] * W_r2m[k * 32 + j];
    WcombB[o * 32 + j] = f2bf(s);
  } else if (idx < 65536 + 256 + 4096 + 32768) {
    int q = idx - (65536 + 256 + 4096);
    Wm2nB[q] = f2bf(W_m2n[q]);
  }
}

// ---------------- bf16 MFMA GEMM: C[M][NC] = A[M][K] @ B[NC][K]^T (+bias) ----
// A_F32: A is f32, converted to bf16 during LDS staging (rows clamped to M-1).
template <bool HAS_BIAS, bool A_F32>
__global__ __launch_bounds__(256) void gemm_mfma(const void* __restrict__ Av,
                                                 const unsigned short* __restrict__ B,
                                                 const float* __restrict__ bias,
                                                 float* __restrict__ C,
                                                 int M, int NC, int K) {
  __shared__ short As[128 * 32];
  __shared__ short Bs[128 * 32];
  const int tid = threadIdx.x;
  const int lane = tid & 63;
  const int wv = tid >> 6;
  const int rowBase = blockIdx.x << 7;
  const int colBase = blockIdx.y << 7;
  const int wrow = (wv & 1) << 6;
  const int wcol = (wv >> 1) << 6;

  const int srow = tid >> 2;
  const int skc = (tid & 3) << 3;

  const int n0 = lane & 15;
  const int q = lane >> 4;

  float4v acc[4][4];
#pragma unroll
  for (int i = 0; i < 4; ++i)
#pragma unroll
    for (int j = 0; j < 4; ++j) acc[i][j] = (float4v)(0.f);

  for (int k0 = 0; k0 < K; k0 += 32) {
    uint4 a0, a1;
    if (A_F32) {
      const float* Af = (const float*)Av;
      const int r0 = min(rowBase + srow, M - 1);
      const int r1 = min(rowBase + 64 + srow, M - 1);
      const float* p0 = Af + (size_t)r0 * K + k0 + skc;
      const float* p1 = Af + (size_t)r1 * K + k0 + skc;
      float4 x0 = ((const float4*)p0)[0], x1 = ((const float4*)p0)[1];
      float4 y0 = ((const float4*)p1)[0], y1 = ((const float4*)p1)[1];
      a0 = pack8(x0, x1);
      a1 = pack8(y0, y1);
    } else {
      const unsigned short* Ab = (const unsigned short*)Av;
      a0 = *(const uint4*)(Ab + (size_t)(unsigned)(rowBase + srow) * K + k0 + skc);
      a1 = *(const uint4*)(Ab + (size_t)(unsigned)(rowBase + 64 + srow) * K + k0 + skc);
    }
    uint4 b0 = *(const uint4*)(B + (size_t)(unsigned)(colBase + srow) * K + k0 + skc);
    uint4 b1 = *(const uint4*)(B + (size_t)(unsigned)(colBase + 64 + srow) * K + k0 + skc);
    __syncthreads();
    ((uint4*)As)[tid] = a0;
    ((uint4*)As)[256 + tid] = a1;
    ((uint4*)Bs)[tid] = b0;
    ((uint4*)Bs)[256 + tid] = b1;
    __syncthreads();

    short8 af[4], bf[4];
    const short8* Ap = (const short8*)As;
    const short8* Bp = (const short8*)Bs;
#pragma unroll
    for (int i = 0; i < 4; ++i) af[i] = Ap[(wrow + i * 16 + n0) * 4 + q];
#pragma unroll
    for (int j = 0; j < 4; ++j) bf[j] = Bp[(wcol + j * 16 + n0) * 4 + q];
#pragma unroll
    for (int i = 0; i < 4; ++i)
#pragma unroll
      for (int j = 0; j < 4; ++j)
        acc[i][j] = __builtin_amdgcn_mfma_f32_16x16x32_bf16(af[i], bf[j], acc[i][j], 0, 0, 0);
  }

#pragma unroll
  for (int j = 0; j < 4; ++j) {
    const int col = colBase + wcol + j * 16 + n0;
    const float bv = HAS_BIAS ? bias[col] : 0.f;
#pragma unroll
    for (int i = 0; i < 4; ++i) {
      const int row0 = rowBase + wrow + i * 16 + (q << 2);
#pragma unroll
      for (int r = 0; r < 4; ++r) {
        const int row = row0 + r;
        if (row < M) C[(unsigned)row * NC + col] = acc[i][j][r] + bv;
      }
    }
  }
}

// ---------------- CSR build: histogram ----------------
__global__ void k_hist(const int* __restrict__ dst, int* __restrict__ degi) {
  unsigned e = blockIdx.x * blockDim.x + threadIdx.x;
  if (e < N_EDGES) atomicAdd(&degi[dst[e]], 1);
}

// ---------------- CSR build: single-pass chained scan ----------------
// Ticketed blocks: ticket order == scheduling order, so spinning on the
// predecessor's flag cannot deadlock. flags[b] holds (inclusive_prefix+1).
__global__ __launch_bounds__(1024) void k_scan(const int* __restrict__ degi,
                                               int* __restrict__ row,
                                               int* __restrict__ flags,
                                               int* __restrict__ ticket) {
  __shared__ int sm[1024];
  __shared__ int sh_b, sh_prev;
  const int tid = threadIdx.x;
  if (tid == 0) sh_b = atomicAdd(ticket, 1);
  __syncthreads();
  const int b = sh_b;
  const unsigned i = (unsigned)b * 1024u + tid;
  int v = (i < N_NODES) ? degi[i] : 0;
  sm[tid] = v;
  __syncthreads();
  for (int d = 1; d < 1024; d <<= 1) {
    int t = (tid >= d) ? sm[tid - d] : 0;
    __syncthreads();
    sm[tid] += t;
    __syncthreads();
  }
  const int incl = sm[tid];
  const int total = sm[1023];
  if (tid == 0) {
    int prev = 0;
    if (b > 0) {
      int f;
      while ((f = __hip_atomic_load(&flags[b - 1], __ATOMIC_ACQUIRE,
                                    __HIP_MEMORY_SCOPE_AGENT)) == 0) {
        __builtin_amdgcn_s_sleep(1);
      }
      prev = f - 1;
    }
    __hip_atomic_store(&flags[b], prev + total + 1, __ATOMIC_RELEASE,
                       __HIP_MEMORY_SCOPE_AGENT);
    sh_prev = prev;
  }
  __syncthreads();
  const int base = sh_prev;
  if (i < N_NODES) row[i] = base + incl - v;
  if (b == 0 && tid == 0) row[N_NODES] = N_EDGES;
}

// ---------------- CSR build: scatter edges into rows (int2) ----------------
__global__ void k_scatter(const int* __restrict__ src, const int* __restrict__ dst,
                          const int* __restrict__ row, int* __restrict__ cnt,
                          int2* __restrict__ csrse) {
  unsigned e = blockIdx.x * blockDim.x + threadIdx.x;
  if (e < N_EDGES) {
    int d = dst[e];
    int pos = row[d] + atomicAdd(&cnt[d], 1);
    csrse[pos] = make_int2(src[e], (int)e);
  }
}

// ---------------- fused per-node edge phase (MFMA et, shfl CSR, reg prefetch) --
// One block (128 thr = 2 waves) per destination node. Per CH=16 CSR slots:
//   CSR entries -> lane registers, broadcast via __shfl (no LDS, no barrier)
//   et tile [16][128] = rbf[16][32] @ Wcomb^T via 4 mfma_16x16x32_bf16/wave
//   xl[src] gathers batched into 16 registers (deep MLP) before the edge loop
//   per-edge: u = leaky(xl+xr+et); logit = 16-lane reduce(u*att); p = exp
//   den += p; S += p*xl; etacc += et  (mean(rbf)@Wcomb == mean(et))
// Self-loop via etacc/deg. No atomics; 2 barriers/chunk.
__global__ __launch_bounds__(128) void k_node(
    const float* __restrict__ XLR, const float* __restrict__ rbf,
    const int2* __restrict__ csrse, const int* __restrict__ row,
    const unsigned short* __restrict__ WcombB,
    const float* __restrict__ att, const float* __restrict__ bias,
    unsigned short* __restrict__ accb) {
  __shared__ __align__(16) float et_s[CH][132];
  const int tid = threadIdx.x;
  const int lane = tid & 63;
  const int wv = tid >> 6;       // 0,1
  const int n0 = lane & 15;
  const int q = lane >> 4;
  const int wcol = wv << 6;
  const unsigned n = blockIdx.x;

  const float att_r = att[tid];
  const int off = row[n], end = row[n + 1];
  const float xl_d = XLR[(n << 8) + tid];
  const float xr_d = XLR[(n << 8) + 128 + tid];

  // loop-invariant B-frags: WcombB[128][32] bf16, this wave's 64 output cols
  short8 bfr[4];
#pragma unroll
  for (int j = 0; j < 4; ++j)
    bfr[j] = *(const short8*)(WcombB + (wcol + j * 16 + n0) * 32 + (q << 3));

  float S = 0.f, den = 0.f, etacc = 0.f;

  for (int c0 = off; c0 < end; c0 += CH) {
    const int cnt = min(CH, end - c0);
    // CSR entries into lane registers (both waves redundant; no LDS)
    int sreg = 0, ereg = 0;
    if (lane < cnt) {
      int2 se = csrse[c0 + lane];
      sreg = se.x; ereg = se.y;
    }
    // A-frag: edge row n0, k-elems q*8..q*8+7, from global (zero-fill pad rows)
    const int e_n0 = __shfl(ereg, n0);
    short8 af = (short8)0;
    if (n0 < cnt) {
      const float* rp = rbf + (size_t)(unsigned)e_n0 * 32 + (q << 3);
      float4 v0 = ((const float4*)rp)[0];
      float4 v1 = ((const float4*)rp)[1];
      af[0] = (short)f2bf(v0.x); af[1] = (short)f2bf(v0.y);
      af[2] = (short)f2bf(v0.z); af[3] = (short)f2bf(v0.w);
      af[4] = (short)f2bf(v1.x); af[5] = (short)f2bf(v1.y);
      af[6] = (short)f2bf(v1.z); af[7] = (short)f2bf(v1.w);
    }
    float4v c[4];
#pragma unroll
    for (int j = 0; j < 4; ++j)
      c[j] = __builtin_amdgcn_mfma_f32_16x16x32_bf16(af, bfr[j], (float4v)(0.f), 0, 0, 0);
    __syncthreads();  // previous chunk's et_s readers are done
#pragma unroll
    for (int j = 0; j < 4; ++j)
#pragma unroll
      for (int r = 0; r < 4; ++r)
        et_s[(q << 2) + r][wcol + j * 16 + n0] = c[j][r];
    // batch the xl[src] gathers into registers (16 loads in flight);
    // __shfl with literal lane -> v_readlane -> SGPR base addressing
    float xlr[CH];
#pragma unroll
    for (int i = 0; i < CH; ++i) {
      const unsigned s = (unsigned)__shfl(sreg, i);
      xlr[i] = XLR[(s << 8) + tid];
    }
    __syncthreads();  // et_s tile visible
#pragma unroll
    for (int i = 0; i < CH; ++i) {
      if (i < cnt) {  // block-uniform guard -> scalar branch, keeps unroll
        const float et = et_s[i][tid];
        const float xls = xlr[i];
        float u = xls + xr_d + et;
        u = (u > 0.f) ? u : 0.2f * u;
        float r = u * att_r;
        r += __shfl_xor(r, 1);
        r += __shfl_xor(r, 2);
        r += __shfl_xor(r, 4);
        r += __shfl_xor(r, 8);
        const float p = __expf(r);
        den += p;
        S += p * xls;
        etacc += et;
      }
    }
  }

  // self-loop: et = mean of incoming et rows (linearity of rbf@Wcomb)
  const float inv = 1.f / fmaxf((float)(end - off), 1.f);
  float u = xl_d + xr_d + etacc * inv;
  u = (u > 0.f) ? u : 0.2f * u;
  float r = u * att_r;
  r += __shfl_xor(r, 1);
  r += __shfl_xor(r, 2);
  r += __shfl_xor(r, 4);
  r += __shfl_xor(r, 8);
  const float p = __expf(r);
  den += p;
  S += p * xl_d;

  const float outv = S / den + bias[tid];
  accb[((size_t)n << 7) + tid] = f2bf(outv);
}

extern "C" void kernel_launch(void* const* d_in, const int* in_sizes, int n_in,
                              void* d_out, int out_size, void* d_ws, size_t ws_size,
                              hipStream_t stream) {
  const float* x     = (const float*)d_in[0];
  const float* rbf   = (const float*)d_in[1];
  const int*   ei    = (const int*)d_in[2];
  const float* W_n2m = (const float*)d_in[4];
  const float* W_r2m = (const float*)d_in[5];
  const float* Wl    = (const float*)d_in[6];
  const float* bl    = (const float*)d_in[7];
  const float* Wr    = (const float*)d_in[8];
  const float* br    = (const float*)d_in[9];
  const float* We    = (const float*)d_in[10];
  const float* att   = (const float*)d_in[11];
  const float* bias  = (const float*)d_in[12];
  const float* W_m2n = (const float*)d_in[13];
  float* out = (float*)d_out;
  float* ws  = (float*)d_ws;

  const int* src = ei;
  const int* dst = ei + N_EDGES;

  float* XLR    = ws + OFF_XLR;
  unsigned short* accb = (unsigned short*)(ws + OFF_ACCB);
  int2* csrse  = (int2*)(ws + OFF_CSRSE);
  int* rowoff  = (int*)(ws + OFF_ROW);
  int* cnt     = (int*)(ws + OFF_CNT);
  int* degi    = (int*)(ws + OFF_DEGI);
  int* flags   = (int*)(ws + OFF_FLAGS);
  int* ticket  = flags + 100;
  float* bcat  = ws + OFF_BCAT;
  unsigned short* WcombB = (unsigned short*)(ws + OFF_WCOMBB);
  unsigned short* WcatB  = (unsigned short*)(ws + OFF_WCATB);
  unsigned short* Wm2nB  = (unsigned short*)(ws + OFF_WM2NB);

  // 1. fold weights + zero cnt|degi|flags (one launch)
  k_pre<<<597, 256, 0, stream>>>(Wl, Wr, We, W_n2m, W_r2m, bl, br, W_m2n,
                                 WcatB, bcat, WcombB, Wm2nB, ws + OFF_CNT);
  // 2. CSR build: hist -> chained scan -> scatter
  k_hist<<<N_EDGES / 256, 256, 0, stream>>>(dst, degi);
  k_scan<<<SCAN_NB, 1024, 0, stream>>>(degi, rowoff, flags, ticket);
  k_scatter<<<N_EDGES / 256, 256, 0, stream>>>(src, dst, rowoff, cnt, csrse);
  // 3. XLR = x @ [Wl@W_n2m ; Wr@W_n2m]^T + [bl|br]  (f32->bf16 fused in staging)
  gemm_mfma<true, true><<<dim3(M_PAD / 128, 2), 256, 0, stream>>>(
      x, WcatB, bcat, XLR, N_NODES, 256, 256);
  // 4. fused edge phase: one block per node, MFMA et, no atomics
  k_node<<<N_NODES, 128, 0, stream>>>(XLR, rbf, csrse, rowoff, WcombB,
                                      att, bias, accb);
  // 5. out = acc @ W_m2n^T  (bf16 MFMA)
  gemm_mfma<false, false><<<dim3(M_PAD / 128, 2), 256, 0, stream>>>(
      accb, Wm2nB, nullptr, out, N_NODES, 256, 128);
}